// Round 8
// baseline (93.091 us; speedup 1.0000x reference)
//
#include <hip/hip_runtime.h>
#include <math.h>

#define NROWS 4096
#define DDIM  256
#define BM 128
#define BN 256
#define LOG2E2 2.8853900817779268f   // 2*log2(e): exp(2S) = exp2(LOG2E2 * S)

typedef __attribute__((ext_vector_type(8))) short short8;  // 8 bf16 (4 VGPRs)
typedef __attribute__((ext_vector_type(4))) float f32x4;   // MFMA 16x16 C/D

__device__ __forceinline__ unsigned short f2bf(float f) {  // RNE float->bf16
    unsigned int u = __float_as_uint(f);
    u += 0x7fffu + ((u >> 16) & 1u);
    return (unsigned short)(u >> 16);
}

__device__ __forceinline__ float exp2_fast(float x) {
#if __has_builtin(__builtin_amdgcn_exp2f)
    return __builtin_amdgcn_exp2f(x);
#else
    return exp2f(x);
#endif
}

// ---------------- Kernel 1: L2-normalize rows + positive dots ----------------
// 1 wave per row. pos computed in fp32 (exact); bf16 copies written for MFMA.
// A-side (zi) pre-scaled by 2*log2(e) so the GEMM accumulator is exp2-ready.
// Also zeroes the rowsum/colsum accumulators (8 floats per block).
__global__ __launch_bounds__(256) void normalize_kernel(
    const float* __restrict__ emb_i, const float* __restrict__ emb_j,
    unsigned short* __restrict__ zi, unsigned short* __restrict__ zj,
    float* __restrict__ pos, float* __restrict__ sums /*rowsum..colsum, 2N*/)
{
    if (threadIdx.x < 8) sums[blockIdx.x * 8 + threadIdx.x] = 0.0f;

    const int wave = threadIdx.x >> 6;
    const int lane = threadIdx.x & 63;
    const int row  = blockIdx.x * 4 + wave;

    const float4 vi = *((const float4*)(emb_i + (size_t)row * DDIM) + lane);
    const float4 vj = *((const float4*)(emb_j + (size_t)row * DDIM) + lane);

    float ssi = vi.x*vi.x + vi.y*vi.y + vi.z*vi.z + vi.w*vi.w;
    float ssj = vj.x*vj.x + vj.y*vj.y + vj.z*vj.z + vj.w*vj.w;
    #pragma unroll
    for (int m = 1; m < 64; m <<= 1) {
        ssi += __shfl_xor(ssi, m);
        ssj += __shfl_xor(ssj, m);
    }
    const float ri = 1.0f / fmaxf(sqrtf(ssi), 1e-12f);
    const float rj = 1.0f / fmaxf(sqrtf(ssj), 1e-12f);

    const float zix = vi.x*ri, ziy = vi.y*ri, ziz = vi.z*ri, ziw = vi.w*ri;
    const float zjx = vj.x*rj, zjy = vj.y*rj, zjz = vj.z*rj, zjw = vj.w*rj;

    float p = zix*zjx + ziy*zjy + ziz*zjz + ziw*zjw;
    #pragma unroll
    for (int m = 1; m < 64; m <<= 1) p += __shfl_xor(p, m);
    if (lane == 0) pos[row] = p;

    ushort4 oi = { f2bf(zix*LOG2E2), f2bf(ziy*LOG2E2), f2bf(ziz*LOG2E2), f2bf(ziw*LOG2E2) };
    ushort4 oj = { f2bf(zjx), f2bf(zjy), f2bf(zjz), f2bf(zjw) };
    *((ushort4*)(zi + (size_t)row * DDIM) + lane) = oi;
    *((ushort4*)(zj + (size_t)row * DDIM) + lane) = oj;
}

// ---------- Kernel 2: DIRECT-FROM-L2 bf16 MFMA + exp2 + row/col sums ----------
// zi+zj = 4 MB total -> fully L2-resident. NO LDS, NO barriers (Common-mistake
// #7: staging cache-fit data is pure overhead — the LDS port was the floor).
// 128x256 tile per block, 4 waves (2x2), each wave 64x128 = 4x8 frags of
// 16x16x32 MFMA. Per k-slice: 12 global b128 fragment loads (L2-hit) + 32
// MFMAs, fully unrolled over 8 slices; 2 blocks/CU of async waves hide L2
// latency. Fragment address = row*DDIM + kk*32 + g*8 (identity layout; the
// k-order matches the LDS path already verified absmax=0 in R3-R6).
__global__ __launch_bounds__(256, 2) void gemm_fused_kernel(
    const unsigned short* __restrict__ zi, const unsigned short* __restrict__ zj,
    float* __restrict__ rowsum, float* __restrict__ colsum)
{
    const int tid  = threadIdx.x;
    const int lane = tid & 63;
    const int wave = tid >> 6;     // 0..3
    const int g    = lane >> 4;    // k-group 0..3
    const int fr   = lane & 15;    // fragment row 0..15
    const int wr   = wave >> 1;    // wave row 0..1 (64-row halves)
    const int wc   = wave & 1;     // wave col 0..1 (128-col halves)
    const int bm   = blockIdx.x * BM;
    const int bn   = blockIdx.y * BN;

    f32x4 acc[4][8] = {};          // 128 VGPR; all indices compile-time

    // Per-lane fragment base pointers (k-offset g*8 folded in).
    const unsigned short* pA = zi + (size_t)(bm + wr * 64  + fr) * DDIM + g * 8;
    const unsigned short* pB = zj + (size_t)(bn + wc * 128 + fr) * DDIM + g * 8;

    #pragma unroll
    for (int kk = 0; kk < 8; ++kk) {        // k-slice of 32 (one MFMA depth)
        short8 a[4], b[8];
        #pragma unroll
        for (int mi = 0; mi < 4; ++mi)
            a[mi] = *(const short8*)(pA + (size_t)mi * 16 * DDIM + kk * 32);
        #pragma unroll
        for (int ni = 0; ni < 8; ++ni)
            b[ni] = *(const short8*)(pB + (size_t)ni * 16 * DDIM + kk * 32);
        #pragma unroll
        for (int mi = 0; mi < 4; ++mi)
            #pragma unroll
            for (int ni = 0; ni < 8; ++ni)
                acc[mi][ni] = __builtin_amdgcn_mfma_f32_16x16x32_bf16(
                    a[mi], b[ni], acc[mi][ni], 0, 0, 0);
    }

    // Epilogue. acc[mi][ni][j] = LOG2E2 * S at row bm+wr*64+mi*16+g*4+j,
    // col bn+wc*128+ni*16+fr (C/D layout verified absmax=0 in R3-R6).
    float rp[4][4];
    float cp[8] = {0.f,0.f,0.f,0.f,0.f,0.f,0.f,0.f};
    #pragma unroll
    for (int mi = 0; mi < 4; ++mi)
        #pragma unroll
        for (int j = 0; j < 4; ++j) rp[mi][j] = 0.f;

    #pragma unroll
    for (int mi = 0; mi < 4; ++mi)
        #pragma unroll
        for (int ni = 0; ni < 8; ++ni)
            #pragma unroll
            for (int j = 0; j < 4; ++j) {
                const float e = exp2_fast(acc[mi][ni][j]);
                rp[mi][j] += e;
                cp[ni]    += e;
            }

    // Row sums: reduce over cols = lane bits 0..3.
    #pragma unroll
    for (int mi = 0; mi < 4; ++mi)
        #pragma unroll
        for (int j = 0; j < 4; ++j) {
            float v = rp[mi][j];
            v += __shfl_xor(v, 1); v += __shfl_xor(v, 2);
            v += __shfl_xor(v, 4); v += __shfl_xor(v, 8);
            if (fr == 0)
                atomicAdd(&rowsum[bm + wr * 64 + mi * 16 + g * 4 + j], v);
        }

    // Col sums: reduce over row-groups = lane bits 4,5.
    #pragma unroll
    for (int ni = 0; ni < 8; ++ni) {
        float v = cp[ni];
        v += __shfl_xor(v, 16); v += __shfl_xor(v, 32);
        if (g == 0)
            atomicAdd(&colsum[bn + wc * 128 + ni * 16 + fr], v);
    }
}

// ---------------- Kernel 3: final loss reduction ----------------
__global__ __launch_bounds__(512) void finalize_kernel(
    const float* __restrict__ pos, const float* __restrict__ rowsum,
    const float* __restrict__ colsum, float* __restrict__ out)
{
    float s = 0.0f;
    for (int r = threadIdx.x; r < NROWS; r += 512) {
        // log(0.5*a) + log(0.5*b) = log(0.25*a*b)
        s += -4.0f * pos[r] + logf(0.25f * rowsum[r] * colsum[r]);
    }
    __shared__ float part[8];
    #pragma unroll
    for (int m = 1; m < 64; m <<= 1) s += __shfl_xor(s, m);
    if ((threadIdx.x & 63) == 0) part[threadIdx.x >> 6] = s;
    __syncthreads();
    if (threadIdx.x == 0) {
        float t = 0.f;
        #pragma unroll
        for (int w = 0; w < 8; ++w) t += part[w];
        out[0] = t / (2.0f * NROWS);
    }
}

extern "C" void kernel_launch(void* const* d_in, const int* in_sizes, int n_in,
                              void* d_out, int out_size, void* d_ws, size_t ws_size,
                              hipStream_t stream)
{
    const float* emb_i = (const float*)d_in[0];
    const float* emb_j = (const float*)d_in[1];

    unsigned short* zi = (unsigned short*)d_ws;               // N*D bf16 (scaled)
    unsigned short* zj = zi + (size_t)NROWS * DDIM;           // N*D bf16
    float* pos    = (float*)(zj + (size_t)NROWS * DDIM);      // N
    float* rowsum = pos + NROWS;                              // N
    float* colsum = rowsum + NROWS;                           // N (contiguous)

    normalize_kernel<<<NROWS / 4, 256, 0, stream>>>(emb_i, emb_j, zi, zj, pos, rowsum);

    dim3 grid(NROWS / BM, NROWS / BN);   // 32 x 16 = 512 blocks, 2/CU, 1 round
    gemm_fused_kernel<<<grid, 256, 0, stream>>>(zi, zj, rowsum, colsum);

    finalize_kernel<<<1, 512, 0, stream>>>(pos, rowsum, colsum, (float*)d_out);
}

// Round 9
// 81.242 us; speedup vs baseline: 1.1458x; 1.1458x over previous
//
#include <hip/hip_runtime.h>
#include <math.h>

#define NROWS 4096
#define DDIM  256
#define BM 128
#define BN 256
#define BK 32
#define LOG2E2 2.8853900817779268f   // 2*log2(e): exp(2S) = exp2(LOG2E2 * S)

typedef __attribute__((ext_vector_type(8))) short short8;  // 8 bf16 (4 VGPRs)
typedef __attribute__((ext_vector_type(4))) float f32x4;   // MFMA 16x16 C/D

__device__ __forceinline__ unsigned short f2bf(float f) {  // RNE float->bf16
    unsigned int u = __float_as_uint(f);
    u += 0x7fffu + ((u >> 16) & 1u);
    return (unsigned short)(u >> 16);
}

__device__ __forceinline__ float exp2_fast(float x) {
#if __has_builtin(__builtin_amdgcn_exp2f)
    return __builtin_amdgcn_exp2f(x);
#else
    return exp2f(x);
#endif
}

// global -> LDS direct DMA, 16B per lane. LDS dest is wave-uniform base
// (lane offset implicit +lane*16); global src is per-lane (pre-swizzled).
#define GLOAD_LDS16(gsrc, ldst)                                          \
    __builtin_amdgcn_global_load_lds(                                    \
        (__attribute__((address_space(1))) void*)(gsrc),                 \
        (__attribute__((address_space(3))) void*)(ldst), 16, 0, 0)

// ---------------- Kernel 1: L2-normalize rows + positive dots ----------------
// 1 wave per row. pos computed in fp32 (exact); bf16 copies written for MFMA.
// A-side (zi) pre-scaled by 2*log2(e) so the GEMM accumulator is exp2-ready.
// Also zeroes the rowsum/colsum accumulators (8 floats per block).
__global__ __launch_bounds__(256) void normalize_kernel(
    const float* __restrict__ emb_i, const float* __restrict__ emb_j,
    unsigned short* __restrict__ zi, unsigned short* __restrict__ zj,
    float* __restrict__ pos, float* __restrict__ sums /*rowsum..colsum, 2N*/)
{
    if (threadIdx.x < 8) sums[blockIdx.x * 8 + threadIdx.x] = 0.0f;

    const int wave = threadIdx.x >> 6;
    const int lane = threadIdx.x & 63;
    const int row  = blockIdx.x * 4 + wave;

    const float4 vi = *((const float4*)(emb_i + (size_t)row * DDIM) + lane);
    const float4 vj = *((const float4*)(emb_j + (size_t)row * DDIM) + lane);

    float ssi = vi.x*vi.x + vi.y*vi.y + vi.z*vi.z + vi.w*vi.w;
    float ssj = vj.x*vj.x + vj.y*vj.y + vj.z*vj.z + vj.w*vj.w;
    #pragma unroll
    for (int m = 1; m < 64; m <<= 1) {
        ssi += __shfl_xor(ssi, m);
        ssj += __shfl_xor(ssj, m);
    }
    const float ri = 1.0f / fmaxf(sqrtf(ssi), 1e-12f);
    const float rj = 1.0f / fmaxf(sqrtf(ssj), 1e-12f);

    const float zix = vi.x*ri, ziy = vi.y*ri, ziz = vi.z*ri, ziw = vi.w*ri;
    const float zjx = vj.x*rj, zjy = vj.y*rj, zjz = vj.z*rj, zjw = vj.w*rj;

    float p = zix*zjx + ziy*zjy + ziz*zjz + ziw*zjw;
    #pragma unroll
    for (int m = 1; m < 64; m <<= 1) p += __shfl_xor(p, m);
    if (lane == 0) pos[row] = p;

    ushort4 oi = { f2bf(zix*LOG2E2), f2bf(ziy*LOG2E2), f2bf(ziz*LOG2E2), f2bf(ziw*LOG2E2) };
    ushort4 oj = { f2bf(zjx), f2bf(zjy), f2bf(zjz), f2bf(zjw) };
    *((ushort4*)(zi + (size_t)row * DDIM) + lane) = oi;
    *((ushort4*)(zj + (size_t)row * DDIM) + lane) = oj;
}

// ---------- Kernel 2: bf16 MFMA S-tile + exp2 + row/col partial sums ----------
// 128x256 tile, 4 waves (2x2), each wave 64x128 = 4x8 frags of 16x16x32 MFMA.
// BK=32 DOUBLE-BUFFERED (T3-minimum 2-phase): stage(t+1) issued BEFORE
// compute(t); the end-of-iter barrier's vmcnt(0) drain lands after a full
// compute phase, so prefetch latency is hidden. LDS 2x(8+16)KB = 48KB keeps
// 2 blocks/CU (sibling-block overlap preserved — the R4 mistake avoided).
// Swizzle for 4-slot rows: slot ^= (row>>1)&3 on source AND read (rule #21);
// word = 4*(g^((fr>>1)&3)) + 16*(fr&1) -> 8 bank-groups x 2 lanes = free.
__global__ __launch_bounds__(256, 2) void gemm_fused_kernel(
    const unsigned short* __restrict__ zi, const unsigned short* __restrict__ zj,
    float* __restrict__ rowsum, float* __restrict__ colsum)
{
    __shared__ unsigned short As[2][BM * BK];   // 2 x 8 KiB
    __shared__ unsigned short Bs[2][BN * BK];   // 2 x 16 KiB

    const int tid  = threadIdx.x;
    const int lane = tid & 63;
    const int wave = tid >> 6;     // 0..3
    const int g    = lane >> 4;    // k-group 0..3
    const int fr   = lane & 15;    // fragment row 0..15
    const int wr   = wave >> 1;    // wave row 0..1 (64-row halves)
    const int wc   = wave & 1;     // wave col 0..1 (128-col halves)
    const int bm   = blockIdx.x * BM;
    const int bn   = blockIdx.y * BN;

    f32x4 acc[4][8] = {};          // 128 VGPR; all indices compile-time

    auto stage = [&](int buf, int k0) {
        // A: 128 rows x 4 slots = 512 granules = 2 rounds of 256 threads.
        #pragma unroll
        for (int it = 0; it < 2; ++it) {
            const int L   = it * 256 + tid;
            const int row = L >> 2;
            const int sl  = (L & 3) ^ ((row >> 1) & 3);
            GLOAD_LDS16(zi + (size_t)(bm + row) * DDIM + k0 + sl * 8,
                        &As[buf][(it * 256 + wave * 64) << 3]);
        }
        // B: 256 rows x 4 slots = 1024 granules = 4 rounds.
        #pragma unroll
        for (int it = 0; it < 4; ++it) {
            const int L   = it * 256 + tid;
            const int row = L >> 2;
            const int sl  = (L & 3) ^ ((row >> 1) & 3);
            GLOAD_LDS16(zj + (size_t)(bn + row) * DDIM + k0 + sl * 8,
                        &Bs[buf][(it * 256 + wave * 64) << 3]);
        }
    };

    auto compute = [&](int buf) {
        const int coff = ((g ^ ((fr >> 1) & 3)) << 3);   // swizzled k-slot
        short8 a[4], b[8];
        #pragma unroll
        for (int mi = 0; mi < 4; ++mi)
            a[mi] = *(const short8*)&As[buf][(wr * 64 + mi * 16 + fr) * BK + coff];
        #pragma unroll
        for (int ni = 0; ni < 8; ++ni)
            b[ni] = *(const short8*)&Bs[buf][(wc * 128 + ni * 16 + fr) * BK + coff];
        #pragma unroll
        for (int mi = 0; mi < 4; ++mi)
            #pragma unroll
            for (int ni = 0; ni < 8; ++ni)
                acc[mi][ni] = __builtin_amdgcn_mfma_f32_16x16x32_bf16(
                    a[mi], b[ni], acc[mi][ni], 0, 0, 0);
    };

    stage(0, 0);
    __syncthreads();                       // drain prologue stage
    #pragma unroll
    for (int t = 0; t < 8; ++t) {          // 8 K-steps of 32
        if (t < 7) stage((t + 1) & 1, (t + 1) * BK);   // prefetch next
        compute(t & 1);
        if (t < 7) __syncthreads();        // vmcnt(0) after full compute phase
    }

    // Epilogue. acc[mi][ni][j] = LOG2E2 * S at row bm+wr*64+mi*16+g*4+j,
    // col bn+wc*128+ni*16+fr (C/D layout verified absmax=0 in R3-R8).
    float rp[4][4];
    float cp[8] = {0.f,0.f,0.f,0.f,0.f,0.f,0.f,0.f};
    #pragma unroll
    for (int mi = 0; mi < 4; ++mi)
        #pragma unroll
        for (int j = 0; j < 4; ++j) rp[mi][j] = 0.f;

    #pragma unroll
    for (int mi = 0; mi < 4; ++mi)
        #pragma unroll
        for (int ni = 0; ni < 8; ++ni)
            #pragma unroll
            for (int j = 0; j < 4; ++j) {
                const float e = exp2_fast(acc[mi][ni][j]);
                rp[mi][j] += e;
                cp[ni]    += e;
            }

    // Row sums: reduce over cols = lane bits 0..3.
    #pragma unroll
    for (int mi = 0; mi < 4; ++mi)
        #pragma unroll
        for (int j = 0; j < 4; ++j) {
            float v = rp[mi][j];
            v += __shfl_xor(v, 1); v += __shfl_xor(v, 2);
            v += __shfl_xor(v, 4); v += __shfl_xor(v, 8);
            if (fr == 0)
                atomicAdd(&rowsum[bm + wr * 64 + mi * 16 + g * 4 + j], v);
        }

    // Col sums: reduce over row-groups = lane bits 4,5.
    #pragma unroll
    for (int ni = 0; ni < 8; ++ni) {
        float v = cp[ni];
        v += __shfl_xor(v, 16); v += __shfl_xor(v, 32);
        if (g == 0)
            atomicAdd(&colsum[bn + wc * 128 + ni * 16 + fr], v);
    }
}

// ---------------- Kernel 3: final loss reduction ----------------
__global__ __launch_bounds__(512) void finalize_kernel(
    const float* __restrict__ pos, const float* __restrict__ rowsum,
    const float* __restrict__ colsum, float* __restrict__ out)
{
    float s = 0.0f;
    for (int r = threadIdx.x; r < NROWS; r += 512) {
        // log(0.5*a) + log(0.5*b) = log(0.25*a*b)
        s += -4.0f * pos[r] + logf(0.25f * rowsum[r] * colsum[r]);
    }
    __shared__ float part[8];
    #pragma unroll
    for (int m = 1; m < 64; m <<= 1) s += __shfl_xor(s, m);
    if ((threadIdx.x & 63) == 0) part[threadIdx.x >> 6] = s;
    __syncthreads();
    if (threadIdx.x == 0) {
        float t = 0.f;
        #pragma unroll
        for (int w = 0; w < 8; ++w) t += part[w];
        out[0] = t / (2.0f * NROWS);
    }
}

extern "C" void kernel_launch(void* const* d_in, const int* in_sizes, int n_in,
                              void* d_out, int out_size, void* d_ws, size_t ws_size,
                              hipStream_t stream)
{
    const float* emb_i = (const float*)d_in[0];
    const float* emb_j = (const float*)d_in[1];

    unsigned short* zi = (unsigned short*)d_ws;               // N*D bf16 (scaled)
    unsigned short* zj = zi + (size_t)NROWS * DDIM;           // N*D bf16
    float* pos    = (float*)(zj + (size_t)NROWS * DDIM);      // N
    float* rowsum = pos + NROWS;                              // N
    float* colsum = rowsum + NROWS;                           // N (contiguous)

    normalize_kernel<<<NROWS / 4, 256, 0, stream>>>(emb_i, emb_j, zi, zj, pos, rowsum);

    dim3 grid(NROWS / BM, NROWS / BN);   // 32 x 16 = 512 blocks, 2/CU, 1 round
    gemm_fused_kernel<<<grid, 256, 0, stream>>>(zi, zj, rowsum, colsum);

    finalize_kernel<<<1, 512, 0, stream>>>(pos, rowsum, colsum, (float*)d_out);
}

// Round 10
// 77.696 us; speedup vs baseline: 1.1981x; 1.0456x over previous
//
#include <hip/hip_runtime.h>
#include <math.h>

#define NROWS 4096
#define DDIM  256
#define BM 128
#define BN 256
#define BK 64
#define LOG2E2 2.8853900817779268f   // 2*log2(e): exp(2S) = exp2(LOG2E2 * S)

typedef __attribute__((ext_vector_type(4))) float f32x4;   // MFMA 16x16 C/D

__device__ __forceinline__ float exp2_fast(float x) {
#if __has_builtin(__builtin_amdgcn_exp2f)
    return __builtin_amdgcn_exp2f(x);
#else
    return exp2f(x);
#endif
}

// ---- float -> fp8 e4m3 (OCP) ----
__device__ __forceinline__ unsigned char f2e4m3(float f) {
    unsigned int u = __float_as_uint(f);
    unsigned int s = (u >> 24) & 0x80;
    float a = fabsf(f);
    if (a >= 448.0f) return (unsigned char)(s | 0x7E);
    if (a < 0.0009765625f) return (unsigned char)s;        // < 2^-10 -> 0
    int exp = (int)((u >> 23) & 0xFF) - 127;
    if (exp < -6) {                                        // subnormal: units of 2^-9
        int t = (int)(a * 512.0f + 0.5f);
        return (unsigned char)(s | (unsigned char)t);
    }
    unsigned int r = u + 0x0007FFFF + ((u >> 20) & 1);     // RNE to 3 mantissa bits
    exp = (int)((r >> 23) & 0xFF) - 127;
    if (exp > 8) return (unsigned char)(s | 0x7E);
    unsigned int mant = (r >> 20) & 7;
    return (unsigned char)(s | (unsigned int)((exp + 7) << 3) | mant);
}

__device__ __forceinline__ unsigned int pack4_e4m3(float a, float b, float c, float d) {
#if __has_builtin(__builtin_amdgcn_cvt_pk_fp8_f32)
    int v = __builtin_amdgcn_cvt_pk_fp8_f32(a, b, 0, 0);       // bytes 0,1
    v = __builtin_amdgcn_cvt_pk_fp8_f32(c, d, v, 1);           // bytes 2,3
    return (unsigned int)v;
#else
    return (unsigned int)f2e4m3(a) | ((unsigned int)f2e4m3(b) << 8) |
           ((unsigned int)f2e4m3(c) << 16) | ((unsigned int)f2e4m3(d) << 24);
#endif
}

// global -> LDS direct DMA, 16B per lane. LDS dest is wave-uniform base
// (lane offset implicit +lane*16); global src is per-lane (pre-swizzled).
#define GLOAD_LDS16(gsrc, ldst)                                          \
    __builtin_amdgcn_global_load_lds(                                    \
        (__attribute__((address_space(1))) void*)(gsrc),                 \
        (__attribute__((address_space(3))) void*)(ldst), 16, 0, 0)

// ---------------- Kernel 1: L2-normalize rows + positive dots ----------------
// 1 wave per row. pos computed in fp32 (exact); fp8 e4m3 copies for MFMA.
// A-side (zi) pre-scaled by 2*log2(e) so the GEMM accumulator is exp2-ready
// (relative fp8 error is scale-invariant). Also zeroes row/col accumulators.
__global__ __launch_bounds__(256) void normalize_kernel(
    const float* __restrict__ emb_i, const float* __restrict__ emb_j,
    unsigned char* __restrict__ zi, unsigned char* __restrict__ zj,
    float* __restrict__ pos, float* __restrict__ sums /*rowsum..colsum, 2N*/)
{
    if (threadIdx.x < 8) sums[blockIdx.x * 8 + threadIdx.x] = 0.0f;

    const int wave = threadIdx.x >> 6;
    const int lane = threadIdx.x & 63;
    const int row  = blockIdx.x * 4 + wave;

    const float4 vi = *((const float4*)(emb_i + (size_t)row * DDIM) + lane);
    const float4 vj = *((const float4*)(emb_j + (size_t)row * DDIM) + lane);

    float ssi = vi.x*vi.x + vi.y*vi.y + vi.z*vi.z + vi.w*vi.w;
    float ssj = vj.x*vj.x + vj.y*vj.y + vj.z*vj.z + vj.w*vj.w;
    #pragma unroll
    for (int m = 1; m < 64; m <<= 1) {
        ssi += __shfl_xor(ssi, m);
        ssj += __shfl_xor(ssj, m);
    }
    const float ri = 1.0f / fmaxf(sqrtf(ssi), 1e-12f);
    const float rj = 1.0f / fmaxf(sqrtf(ssj), 1e-12f);

    const float zix = vi.x*ri, ziy = vi.y*ri, ziz = vi.z*ri, ziw = vi.w*ri;
    const float zjx = vj.x*rj, zjy = vj.y*rj, zjz = vj.z*rj, zjw = vj.w*rj;

    float p = zix*zjx + ziy*zjy + ziz*zjz + ziw*zjw;
    #pragma unroll
    for (int m = 1; m < 64; m <<= 1) p += __shfl_xor(p, m);
    if (lane == 0) pos[row] = p;

    *(unsigned int*)(zi + (size_t)row * DDIM + lane * 4) =
        pack4_e4m3(zix*LOG2E2, ziy*LOG2E2, ziz*LOG2E2, ziw*LOG2E2);
    *(unsigned int*)(zj + (size_t)row * DDIM + lane * 4) =
        pack4_e4m3(zjx, zjy, zjz, zjw);
}

// ---------- Kernel 2: fp8 MFMA S-tile + exp2 + row/col partial sums ----------
// R6-optimal structure (128x256 tile, 4 waves 2x2, 2 blocks/CU, 512 blocks =
// all co-resident) with fp8 operands: staged bytes 96->48 MB, LDS 48->24 KB,
// ds_read bytes halved; MFMA rate unchanged (non-scaled fp8 = bf16 rate).
// Rows are 256 B; BK=64 B = 4 x 16B slots. Swizzle: slot ^= row&3 on the
// pre-swizzled global SOURCE and on the read (rule #21, involution).
// Fragment read = ds_read_b64 (8 B/lane): 4-way bank conflict worst case
// (1.58x on halved traffic = net cheaper than bf16's free 2-way full traffic).
__global__ __launch_bounds__(256, 2) void gemm_fused_kernel(
    const unsigned char* __restrict__ zi, const unsigned char* __restrict__ zj,
    float* __restrict__ rowsum, float* __restrict__ colsum)
{
    __shared__ unsigned char As[BM * BK];   // 8 KiB
    __shared__ unsigned char Bs[BN * BK];   // 16 KiB

    const int tid  = threadIdx.x;
    const int lane = tid & 63;
    const int wave = tid >> 6;     // 0..3
    const int g    = lane >> 4;    // k-group 0..3
    const int fr   = lane & 15;    // fragment row 0..15
    const int wr   = wave >> 1;    // wave row 0..1 (64-row halves)
    const int wc   = wave & 1;     // wave col 0..1 (128-col halves)
    const int bm   = blockIdx.x * BM;
    const int bn   = blockIdx.y * BN;

    f32x4 acc[4][8] = {};          // 128 VGPR; all indices compile-time

    for (int k0 = 0; k0 < DDIM; k0 += BK) {
        // A: 128 rows x 4 slots = 512 granules = 2 rounds of 256 threads.
        #pragma unroll
        for (int it = 0; it < 2; ++it) {
            const int L   = it * 256 + tid;
            const int row = L >> 2;
            const int sl  = (L & 3) ^ (row & 3);
            GLOAD_LDS16(zi + (size_t)(bm + row) * DDIM + k0 + sl * 16,
                        &As[(it * 256 + wave * 64) * 16]);
        }
        // B: 256 rows x 4 slots = 1024 granules = 4 rounds.
        #pragma unroll
        for (int it = 0; it < 4; ++it) {
            const int L   = it * 256 + tid;
            const int row = L >> 2;
            const int sl  = (L & 3) ^ (row & 3);
            GLOAD_LDS16(zj + (size_t)(bn + row) * DDIM + k0 + sl * 16,
                        &Bs[(it * 256 + wave * 64) * 16]);
        }
        __syncthreads();   // drain staging (compiler emits vmcnt(0) first)

        #pragma unroll
        for (int kk = 0; kk < 2; ++kk) {
            // lane's 8 bytes: k = kk*32 + g*8 .. +8 -> slot = kk*2 + (g>>1),
            // byte-in-slot = (g&1)*8; un-swizzle slot with fr&3 (== row&3).
            const int slot = kk * 2 + (g >> 1);
            const int boff = ((slot ^ (fr & 3)) << 4) + ((g & 1) << 3);
            long long a[4], b[8];
            #pragma unroll
            for (int mi = 0; mi < 4; ++mi)
                a[mi] = *(const long long*)&As[(wr * 64 + mi * 16 + fr) * BK + boff];
            #pragma unroll
            for (int ni = 0; ni < 8; ++ni)
                b[ni] = *(const long long*)&Bs[(wc * 128 + ni * 16 + fr) * BK + boff];
            #pragma unroll
            for (int mi = 0; mi < 4; ++mi)
                #pragma unroll
                for (int ni = 0; ni < 8; ++ni)
                    acc[mi][ni] = __builtin_amdgcn_mfma_f32_16x16x32_fp8_fp8(
                        a[mi], b[ni], acc[mi][ni], 0, 0, 0);
        }
        __syncthreads();   // WAR: single-buffer reuse next K-iter
    }

    // Epilogue. acc[mi][ni][j] = LOG2E2 * S at row bm+wr*64+mi*16+g*4+j,
    // col bn+wc*128+ni*16+fr (C/D layout dtype-independent, verified R3-R9).
    float rp[4][4];
    float cp[8] = {0.f,0.f,0.f,0.f,0.f,0.f,0.f,0.f};
    #pragma unroll
    for (int mi = 0; mi < 4; ++mi)
        #pragma unroll
        for (int j = 0; j < 4; ++j) rp[mi][j] = 0.f;

    #pragma unroll
    for (int mi = 0; mi < 4; ++mi)
        #pragma unroll
        for (int ni = 0; ni < 8; ++ni)
            #pragma unroll
            for (int j = 0; j < 4; ++j) {
                const float e = exp2_fast(acc[mi][ni][j]);
                rp[mi][j] += e;
                cp[ni]    += e;
            }

    // Row sums: reduce over cols = lane bits 0..3.
    #pragma unroll
    for (int mi = 0; mi < 4; ++mi)
        #pragma unroll
        for (int j = 0; j < 4; ++j) {
            float v = rp[mi][j];
            v += __shfl_xor(v, 1); v += __shfl_xor(v, 2);
            v += __shfl_xor(v, 4); v += __shfl_xor(v, 8);
            if (fr == 0)
                atomicAdd(&rowsum[bm + wr * 64 + mi * 16 + g * 4 + j], v);
        }

    // Col sums: reduce over row-groups = lane bits 4,5.
    #pragma unroll
    for (int ni = 0; ni < 8; ++ni) {
        float v = cp[ni];
        v += __shfl_xor(v, 16); v += __shfl_xor(v, 32);
        if (g == 0)
            atomicAdd(&colsum[bn + wc * 128 + ni * 16 + fr], v);
    }
}

// ---------------- Kernel 3: final loss reduction ----------------
__global__ __launch_bounds__(512) void finalize_kernel(
    const float* __restrict__ pos, const float* __restrict__ rowsum,
    const float* __restrict__ colsum, float* __restrict__ out)
{
    float s = 0.0f;
    for (int r = threadIdx.x; r < NROWS; r += 512) {
        // log(0.5*a) + log(0.5*b) = log(0.25*a*b)
        s += -4.0f * pos[r] + logf(0.25f * rowsum[r] * colsum[r]);
    }
    __shared__ float part[8];
    #pragma unroll
    for (int m = 1; m < 64; m <<= 1) s += __shfl_xor(s, m);
    if ((threadIdx.x & 63) == 0) part[threadIdx.x >> 6] = s;
    __syncthreads();
    if (threadIdx.x == 0) {
        float t = 0.f;
        #pragma unroll
        for (int w = 0; w < 8; ++w) t += part[w];
        out[0] = t / (2.0f * NROWS);
    }
}

extern "C" void kernel_launch(void* const* d_in, const int* in_sizes, int n_in,
                              void* d_out, int out_size, void* d_ws, size_t ws_size,
                              hipStream_t stream)
{
    const float* emb_i = (const float*)d_in[0];
    const float* emb_j = (const float*)d_in[1];

    unsigned char* zi = (unsigned char*)d_ws;                 // N*D fp8 (scaled)
    unsigned char* zj = zi + (size_t)NROWS * DDIM;            // N*D fp8
    float* pos    = (float*)(zj + (size_t)NROWS * DDIM);      // N
    float* rowsum = pos + NROWS;                              // N
    float* colsum = rowsum + NROWS;                           // N (contiguous)

    normalize_kernel<<<NROWS / 4, 256, 0, stream>>>(emb_i, emb_j, zi, zj, pos, rowsum);

    dim3 grid(NROWS / BM, NROWS / BN);   // 32 x 16 = 512 blocks, 2/CU, 1 round
    gemm_fused_kernel<<<grid, 256, 0, stream>>>(zi, zj, rowsum, colsum);

    finalize_kernel<<<1, 512, 0, stream>>>(pos, rowsum, colsum, (float*)d_out);
}